// Round 2
// 54.545 us; speedup vs baseline: 1.3207x; 1.3207x over previous
//
#include <hip/hip_runtime.h>

// Slab-ocean 1D explicit Euler, parallel-in-time via affine decomposition.
//   z = U + iV,  z_{n+1} = a*z_n + b_n,  a = (1 - dt*K1) + i*(-dt*fc) const,
//   b_n = dt*K0*(tax_n + i*tay_n), affine in n within each forcing hour.
// CH=60 steps (1 forcing hour) per chunk, NCH=672 chunks.
//   Pass 1 (fused scan): one wave per point. Stage the point's forcing rows in
//           LDS, compute closed-form chunk partials S_k inline (geometric sums
//           of the affine forcing against powers of a), then wave-parallel
//           Kogge-Stone scan of affine maps -> chunk start states ZS.
//   Pass 2 (write): re-run each chunk from its exact start state, writing U
//           rows with nontemporal float4 stores (write-BW bound: 165 MB).

#define NT    40320
#define BPTS  1024
#define NF    672
#define NSUB  60
#define CH    60                 // steps per chunk = 1 forcing hour
#define NCH   (NT / CH)          // 672
#define CPL   11                 // chunks per lane in scan (64*11=704 >= 672)
#define PPT   4                  // points per thread in write -> float4 stores
#define WPB   4                  // waves (points) per scan block

typedef float vf4 __attribute__((ext_vector_type(4)));  // clang vector: ok for nontemporal builtin

__device__ __forceinline__ void coefs(const float* pk, const float* fcp, const int* dtp,
                                      float& ar, float& ai, float& bs) {
    float dtf = (float)dtp[0];
    float K0 = expf(pk[0]);
    float K1 = expf(pk[1]);
    ar = 1.0f - dtf * K1;    // Re(a)
    ai = -dtf * fcp[0];      // Im(a)
    bs = dtf * K0;           // forcing scale
}

// Fused pass: chunk partial sums + per-point affine scan.
// grid = BPTS/WPB blocks x 256 threads. One wave per point; lane l owns
// chunks [l*CPL, l*CPL+CPL).
__global__ __launch_bounds__(256)
void slab_scan(const float* __restrict__ pk,
               const float* __restrict__ TAx,
               const float* __restrict__ TAy,
               const float* __restrict__ fcp,
               const int* __restrict__ dtp,
               float2* __restrict__ ZS) {
    const int wave = threadIdx.x >> 6;      // 0..3
    const int l    = threadIdx.x & 63;      // lane within wave
    const int p    = blockIdx.x * WPB + wave;

    // Stage this wave's forcing rows in LDS (coalesced global reads).
    __shared__ float sx[WPB][NF];
    __shared__ float sy[WPB][NF];
    const float* rx = TAx + (size_t)p * NF;
    const float* ry = TAy + (size_t)p * NF;
    for (int t = l; t < NF; t += 64) { sx[wave][t] = rx[t]; sy[wave][t] = ry[t]; }
    __syncthreads();

    float ar, ai, bs;
    coefs(pk, fcp, dtp, ar, ai, bs);

    // One pass over the 60 substeps gives:
    //   g1 = sum_{m<60} a^m ; g2 = sum_{m<60} ((59-m)/60) a^m ; A = a^60
    float g1r = 0.f, g1i = 0.f, g2r = 0.f, g2i = 0.f;
    float pr = 1.f, pi = 0.f;
    for (int m = 0; m < NSUB; ++m) {
        g1r += pr; g1i += pi;
        float w = (float)(NSUB - 1 - m) * (1.0f / NSUB);
        g2r = fmaf(w, pr, g2r); g2i = fmaf(w, pi, g2i);
        float nr = pr * ar - pi * ai;
        float ni = pr * ai + pi * ar;
        pr = nr; pi = ni;
    }
    const float Ar  = pr,        Ai  = pi;         // A = a^CH
    const float cAr = g1r - g2r, cAi = g1i - g2i;  // coeff of w_{f0}
    const float cBr = g2r,       cBi = g2i;        // coeff of w_{f1}

    // Local exclusive prefixes over this lane's CPL chunks (zero-padded tail),
    // with chunk sums S_k computed inline from LDS forcing.
    float qr[CPL], qi[CPL];
    float zr = 0.f, zi = 0.f;
#pragma unroll
    for (int i = 0; i < CPL; ++i) {
        qr[i] = zr; qi[i] = zi;
        const int k = l * CPL + i;
        float sr = 0.f, si = 0.f;
        if (k < NCH) {
            const int f1 = (k + 1 < NF) ? k + 1 : NF - 1;
            float wr0 = bs * sx[wave][k],  wi0 = bs * sy[wave][k];
            float wr1 = bs * sx[wave][f1], wi1 = bs * sy[wave][f1];
            sr = cAr * wr0 - cAi * wi0 + cBr * wr1 - cBi * wi1;
            si = cAr * wi0 + cAi * wr0 + cBr * wi1 + cBi * wr1;
        }
        float nr = Ar * zr - Ai * zi + sr;
        float ni = Ar * zi + Ai * zr + si;
        zr = nr; zi = ni;
    }

    // Segment map: z -> P*z + V with P = A^CPL, V = aggregate.
    float Pr = 1.f, Pi = 0.f;
    for (int m = 0; m < CPL; ++m) {
        float nr = Pr * Ar - Pi * Ai;
        float ni = Pr * Ai + Pi * Ar;
        Pr = nr; Pi = ni;
    }
    float Vr = zr, Vi = zi;

    // Kogge-Stone inclusive scan of affine maps (compose cur after prev).
#pragma unroll
    for (int d = 1; d < 64; d <<= 1) {
        float pr2 = __shfl_up(Pr, d), pi2 = __shfl_up(Pi, d);
        float vr2 = __shfl_up(Vr, d), vi2 = __shfl_up(Vi, d);
        if (l >= d) {
            float nVr = Pr * vr2 - Pi * vi2 + Vr;
            float nVi = Pr * vi2 + Pi * vr2 + Vi;
            float nPr = Pr * pr2 - Pi * pi2;
            float nPi = Pr * pi2 + Pi * pr2;
            Pr = nPr; Pi = nPi; Vr = nVr; Vi = nVi;
        }
    }
    // Exclusive: segment start state E_l = inclusive V of lane l-1.
    float Er = __shfl_up(Vr, 1), Ei = __shfl_up(Vi, 1);
    if (l == 0) { Er = 0.f; Ei = 0.f; }

    // ZS[l*CPL + i] = A^i * E + q_i
#pragma unroll
    for (int i = 0; i < CPL; ++i) {
        const int k = l * CPL + i;
        if (k < NCH)
            ZS[(size_t)k * BPTS + p] = make_float2(Er + qr[i], Ei + qi[i]);
        float nr = Ar * Er - Ai * Ei;
        float ni = Ar * Ei + Ai * Er;
        Er = nr; Ei = ni;
    }
}

// Pass 2: re-run each chunk from its exact start state, writing U each step.
// grid = NCH blocks x 256 threads (one chunk per block, PPT points per thread).
__global__ __launch_bounds__(256)
void slab_write(const float* __restrict__ pk,
                const float* __restrict__ TAx,
                const float* __restrict__ TAy,
                const float* __restrict__ fcp,
                const int* __restrict__ dtp,
                const float2* __restrict__ ZS,
                float* __restrict__ out) {
    const int k  = blockIdx.x;
    const int p0 = threadIdx.x * PPT;

    const int f0 = k;
    const int f1 = (k + 1 < NF) ? k + 1 : NF - 1;

    // Issue all global loads up front; coefficient math overlaps the latency.
    float zr[PPT], zi[PPT];
    float x0[PPT], x1[PPT], y0[PPT], y1[PPT];
#pragma unroll
    for (int j = 0; j < PPT; ++j) {
        float2 z = ZS[(size_t)k * BPTS + p0 + j];
        zr[j] = z.x; zi[j] = z.y;
        const float* rx = TAx + (size_t)(p0 + j) * NF;
        const float* ry = TAy + (size_t)(p0 + j) * NF;
        x0[j] = rx[f0]; x1[j] = rx[f1];
        y0[j] = ry[f0]; y1[j] = ry[f1];
    }

    float ar, ai, bs;
    coefs(pk, fcp, dtp, ar, ai, bs);

    float bx[PPT], by[PPT], dbx[PPT], dby[PPT];
#pragma unroll
    for (int j = 0; j < PPT; ++j) {
        bx[j]  = bs * x0[j];
        by[j]  = bs * y0[j];
        dbx[j] = bs * (x1[j] - x0[j]) * (1.0f / NSUB);
        dby[j] = bs * (y1[j] - y0[j]) * (1.0f / NSUB);
    }

    float* orow = out + (size_t)k * CH * BPTS + p0;

#pragma unroll 10
    for (int s = 0; s < CH; ++s) {
#pragma unroll
        for (int j = 0; j < PPT; ++j) {
            float ur = fmaf(ar, zr[j], fmaf(-ai, zi[j], bx[j]));
            float vi = fmaf(ar, zi[j], fmaf( ai, zr[j], by[j]));
            zr[j] = ur; zi[j] = vi;
            bx[j] += dbx[j]; by[j] += dby[j];
        }
        vf4 v; v.x = zr[0]; v.y = zr[1]; v.z = zr[2]; v.w = zr[3];
        __builtin_nontemporal_store(v, (vf4*)orow);
        orow += BPTS;
    }
}

extern "C" void kernel_launch(void* const* d_in, const int* in_sizes, int n_in,
                              void* d_out, int out_size, void* d_ws, size_t ws_size,
                              hipStream_t stream) {
    const float* pk  = (const float*)d_in[0];
    const float* TAx = (const float*)d_in[1];
    const float* TAy = (const float*)d_in[2];
    const float* fcp = (const float*)d_in[3];
    const int*   dtp = (const int*)d_in[5];   // dt = 60
    float* out = (float*)d_out;

    float2* ZS = (float2*)d_ws;               // [NCH][BPTS]

    slab_scan <<<BPTS / WPB, 256, 0, stream>>>(pk, TAx, TAy, fcp, dtp, ZS);
    slab_write<<<NCH,        256, 0, stream>>>(pk, TAx, TAy, fcp, dtp, ZS, out);
}